// Round 6
// baseline (189.037 us; speedup 1.0000x reference)
//
#include <hip/hip_runtime.h>
#include <hip/hip_bf16.h>

#define NUM_HEADS 4
#define HD 256
#define QD 256
#define VD 256
#define B_SZ 32
#define N_NODES 8192
#define NEG_SLOPE 0.2f

typedef short bf16x8 __attribute__((ext_vector_type(8)));
typedef float f32x4 __attribute__((ext_vector_type(4)));

static __device__ __forceinline__ unsigned short f2bf(float f) {
    __hip_bfloat16 h = __float2bfloat16(f);
    return *reinterpret_cast<unsigned short*>(&h);
}

// ---------------------------------------------------------------------------
// Kernel 1: prep
//  blocks 0..31 : hqb[b][col] = query[b]@Wq[:,col] + 2*bq[col]
//  blocks 32..63: pack Wq -> bf16 fragment order
// ---------------------------------------------------------------------------
__global__ __launch_bounds__(256)
void prep_kernel(const float* __restrict__ query,
                 const float* __restrict__ Wq,
                 const float* __restrict__ bq,
                 unsigned short* __restrict__ WqP,
                 float* __restrict__ hqb) {
    int blk = blockIdx.x;
    int tid = threadIdx.x;
    if (blk < 32) {
        int b = blk, col = tid;
        float acc = 2.0f * bq[col];
#pragma unroll 16
        for (int k = 0; k < QD; ++k)
            acc += query[b * QD + k] * Wq[k * HD + col];
        hqb[b * HD + col] = acc;
    } else {
        int idx = blk - 32;
        int kstep = idx >> 2, g = idx & 3;
        int col = tid;
        unsigned short v[8];
#pragma unroll
        for (int j = 0; j < 8; ++j)
            v[j] = f2bf(Wq[(kstep * 32 + g * 8 + j) * HD + col]);
        *reinterpret_cast<uint4*>(WqP + kstep * 8192 + col * 32 + g * 8) =
            *reinterpret_cast<uint4*>(v);
    }
}

// ---------------------------------------------------------------------------
// Kernel 2 (FUSED flash, low-VGPR): block = (b, 32-row chunk), grid 8192.
// Engineered for <=64 VGPR so 8 waves/SIMD (8 blocks/CU) are resident.
// ---------------------------------------------------------------------------
__global__ __launch_bounds__(256, 8)
void fused_kernel(const float* __restrict__ key,
                  const float* __restrict__ value,
                  const unsigned short* __restrict__ WqP,
                  const float* __restrict__ hqb,
                  const float* __restrict__ avec,
                  float* __restrict__ s,
                  float* __restrict__ p_part,
                  float* __restrict__ pml) {
    __shared__ __align__(16) char smem[17920];
    unsigned short (*kt)[264] = reinterpret_cast<unsigned short(*)[264]>(smem);   // 16896 B
    float (*esr)[4] = reinterpret_cast<float(*)[4]>(smem + 16896);                // raw scores, 512 B
    float (*ese)[4] = reinterpret_cast<float(*)[4]>(smem + 17408);                // exp scores, 512 B
    float (*red)[4][260] = reinterpret_cast<float(*)[4][260]>(smem);              // alias kt (PV reduce)

    int bid = blockIdx.x;
    int b = bid >> 8;
    int n0 = (bid & 255) * 32;
    int tid = threadIdx.x;
    int w = tid >> 6, lane = tid & 63;
    int col16 = lane & 15, g = lane >> 4;

    // ---- stage 32x256 key tile in two halves (low reg pressure)
    {
        int row = tid >> 3, c0 = (tid & 7) * 32;
        const float* kb = key + ((size_t)(b * N_NODES + n0 + row)) * QD + c0;
#pragma unroll
        for (int half = 0; half < 2; ++half) {
            float4 f[4];
#pragma unroll
            for (int i = 0; i < 4; ++i)
                f[i] = *reinterpret_cast<const float4*>(kb + half * 16 + i * 4);
            unsigned int u[8];
#pragma unroll
            for (int j = 0; j < 8; ++j) {
                float lo = (&f[j >> 1].x)[(j & 1) * 2];
                float hi = (&f[j >> 1].x)[(j & 1) * 2 + 1];
                asm("v_cvt_pk_bf16_f32 %0, %1, %2" : "=v"(u[j]) : "v"(lo), "v"(hi));
            }
#pragma unroll
            for (int i = 0; i < 2; ++i) {
                uint4 st = {u[i * 4], u[i * 4 + 1], u[i * 4 + 2], u[i * 4 + 3]};
                *reinterpret_cast<uint4*>(&kt[row][c0 + half * 16 + i * 8]) = st;
            }
        }
    }
    __syncthreads();

    // ---- MFMA: C-tile 32x64 per wave (head w), ct processed in pairs
    f32x4 acc[2][4];
#pragma unroll
    for (int i = 0; i < 2; ++i)
#pragma unroll
        for (int j = 0; j < 4; ++j)
            acc[i][j] = (f32x4){0.f, 0.f, 0.f, 0.f};

#pragma unroll
    for (int ks = 0; ks < 8; ++ks) {
        bf16x8 afr0 = *reinterpret_cast<const bf16x8*>(&kt[col16][ks * 32 + g * 8]);
        bf16x8 afr1 = *reinterpret_cast<const bf16x8*>(&kt[16 + col16][ks * 32 + g * 8]);
        const unsigned short* wp = WqP + ks * 8192 + w * 2048 + g * 8;
#pragma unroll
        for (int cp = 0; cp < 2; ++cp) {
            bf16x8 b0 = *reinterpret_cast<const bf16x8*>(wp + ((cp * 2) * 16 + col16) * 32);
            bf16x8 b1 = *reinterpret_cast<const bf16x8*>(wp + ((cp * 2 + 1) * 16 + col16) * 32);
            acc[0][cp * 2]     = __builtin_amdgcn_mfma_f32_16x16x32_bf16(afr0, b0, acc[0][cp * 2], 0, 0, 0);
            acc[0][cp * 2 + 1] = __builtin_amdgcn_mfma_f32_16x16x32_bf16(afr0, b1, acc[0][cp * 2 + 1], 0, 0, 0);
            acc[1][cp * 2]     = __builtin_amdgcn_mfma_f32_16x16x32_bf16(afr1, b0, acc[1][cp * 2], 0, 0, 0);
            acc[1][cp * 2 + 1] = __builtin_amdgcn_mfma_f32_16x16x32_bf16(afr1, b1, acc[1][cp * 2 + 1], 0, 0, 0);
        }
    }

    // ---- epilogue: leaky_relu + dot(a) + 16-lane reduce -> raw scores in LDS
    {
        float hq_[4], av[4];
#pragma unroll
        for (int ct = 0; ct < 4; ++ct) {
            hq_[ct] = hqb[b * HD + w * 64 + ct * 16 + col16];
            av[ct] = avec[ct * 16 + col16];
        }
#pragma unroll
        for (int rt = 0; rt < 2; ++rt) {
            float part[4] = {0.f, 0.f, 0.f, 0.f};
#pragma unroll
            for (int ct = 0; ct < 4; ++ct) {
#pragma unroll
                for (int r = 0; r < 4; ++r) {
                    float pre = acc[rt][ct][r] + hq_[ct];
                    float t = fmaxf(pre, NEG_SLOPE * pre);
                    part[r] += av[ct] * t;
                }
            }
#pragma unroll
            for (int off = 1; off < 16; off <<= 1)
#pragma unroll
                for (int r = 0; r < 4; ++r)
                    part[r] += __shfl_xor(part[r], off, 64);
            if (col16 == 0) {
                int rloc = rt * 16 + g * 4;
#pragma unroll
                for (int r = 0; r < 4; ++r) esr[rloc + r][w] = part[r];
            }
        }
    }

    // ---- issue value prefetch (latency hidden under softmax + barrier)
    f32x4 vr[8];
    {
        const float* vb = value + ((size_t)(b * N_NODES + n0 + w * 8)) * VD + lane * 4;
#pragma unroll
        for (int r = 0; r < 8; ++r)
            vr[r] = *reinterpret_cast<const f32x4*>(vb + (size_t)r * VD);
    }

    // ---- chunk-local softmax for head w over 32 rows (own wave's column)
    {
        float sv = esr[lane & 31][w];
        float m = sv;
#pragma unroll
        for (int off = 1; off < 32; off <<= 1) m = fmaxf(m, __shfl_xor(m, off, 64));
        float ep = __expf(sv - m);
        float ls = ep;
#pragma unroll
        for (int off = 1; off < 32; off <<= 1) ls += __shfl_xor(ls, off, 64);
        if (lane < 32) ese[lane][w] = ep;
        if (lane == 0) {
            pml[(size_t)bid * 8 + w] = m;
            pml[(size_t)bid * 8 + 4 + w] = ls;
        }
    }
    __syncthreads();   // esr/ese complete; kt MFMA reads retired

    // ---- coalesced raw-score store (128 threads: h = tid>>5, n = tid&31)
    if (tid < 128) {
        int h = tid >> 5, n = tid & 31;
        s[((size_t)(b * NUM_HEADS + h)) * N_NODES + n0 + n] = esr[n][h];
    }

    // ---- weighted value accumulate: wave w owns rows [w*8, w*8+8)
    f32x4 a0 = {0.f, 0.f, 0.f, 0.f}, a1 = a0, a2 = a0, a3 = a0;
#pragma unroll
    for (int r = 0; r < 8; ++r) {
        int n = w * 8 + r;
        f32x4 ev = *reinterpret_cast<const f32x4*>(&ese[n][0]);
        a0 += ev[0] * vr[r];
        a1 += ev[1] * vr[r];
        a2 += ev[2] * vr[r];
        a3 += ev[3] * vr[r];
    }
    *reinterpret_cast<f32x4*>(&red[w][0][lane * 4]) = a0;
    *reinterpret_cast<f32x4*>(&red[w][1][lane * 4]) = a1;
    *reinterpret_cast<f32x4*>(&red[w][2][lane * 4]) = a2;
    *reinterpret_cast<f32x4*>(&red[w][3][lane * 4]) = a3;
    __syncthreads();

    float* pp = p_part + (size_t)bid * 1024;
#pragma unroll
    for (int h = 0; h < 4; ++h)
        pp[h * 256 + tid] = red[0][h][tid] + red[1][h][tid] + red[2][h][tid] + red[3][h][tid];
}

// ---------------------------------------------------------------------------
// Kernel 3: final. Per (b,h): global M, L from 256 chunk (m,l); rescale and
// reduce p_part; p@Wv + bias + relu; emit (M, invL) for epass.
// ---------------------------------------------------------------------------
__global__ __launch_bounds__(256)
void final_kernel(const float* __restrict__ p_part,
                  const float* __restrict__ pml,
                  const float* __restrict__ Wv,
                  const float* __restrict__ bv,
                  float* __restrict__ hout,
                  float* __restrict__ sc) {
    int bh = blockIdx.x;
    int b = bh >> 2, h = bh & 3;
    int tid = threadIdx.x;
    int wv = tid >> 6, lane = tid & 63;

    float mc = pml[((size_t)(b * 256 + tid)) * 8 + h];
    float lc = pml[((size_t)(b * 256 + tid)) * 8 + 4 + h];

    __shared__ float r4a[4], r4b[4];
    float M = mc;
#pragma unroll
    for (int off = 1; off < 64; off <<= 1) M = fmaxf(M, __shfl_xor(M, off, 64));
    if (lane == 0) r4a[wv] = M;
    __syncthreads();
    M = fmaxf(fmaxf(r4a[0], r4a[1]), fmaxf(r4a[2], r4a[3]));

    __shared__ float wfs[256];
    float wf = __expf(mc - M);
    wfs[tid] = wf;
    float Lp = wf * lc;
#pragma unroll
    for (int off = 1; off < 64; off <<= 1) Lp += __shfl_xor(Lp, off, 64);
    if (lane == 0) r4b[wv] = Lp;
    __syncthreads();
    float L = r4b[0] + r4b[1] + r4b[2] + r4b[3];
    float invL = 1.0f / L;
    if (tid == 0) {
        sc[bh * 2] = M;
        sc[bh * 2 + 1] = invL;
    }

    float acc = 0.f;
    const float* pp = p_part + ((size_t)(b * 256)) * 1024 + h * 256 + tid;
#pragma unroll 8
    for (int c = 0; c < 256; ++c)
        acc += wfs[c] * pp[(size_t)c * 1024];
    __shared__ float ps[256];
    ps[tid] = acc * invL;
    __syncthreads();

    int d = tid & 63, kr = tid >> 6;
    float a2 = 0.f;
#pragma unroll 8
    for (int k = kr * 64; k < kr * 64 + 64; ++k)
        a2 += ps[k] * Wv[k * HD + h * 64 + d];
    __shared__ float rs[4][64];
    rs[kr][d] = a2;
    __syncthreads();
    if (tid < 64) {
        float o = bv[h * 64 + tid] + rs[0][tid] + rs[1][tid] + rs[2][tid] + rs[3][tid];
        hout[b * HD + h * 64 + tid] = fmaxf(o, 0.f);
    }
}

// ---------------------------------------------------------------------------
// Kernel 4: e-pass. e_out[b,n,h] = exp(s[b,h,n]-M)*invL (s is L2/L3-hot).
// ---------------------------------------------------------------------------
__global__ __launch_bounds__(256)
void epass_kernel(const float* __restrict__ s,
                  const float* __restrict__ sc,
                  float* __restrict__ e_out) {
    int bid = blockIdx.x;
    int b = bid >> 5, t = bid & 31;
    int n = t * 256 + threadIdx.x;
    float4 ev;
#pragma unroll
    for (int h = 0; h < 4; ++h) {
        float M = sc[(b * 4 + h) * 2];
        float invL = sc[(b * 4 + h) * 2 + 1];
        float sv = s[((size_t)(b * 4 + h)) * N_NODES + n];
        (&ev.x)[h] = __expf(sv - M) * invL;
    }
    *reinterpret_cast<float4*>(e_out + ((size_t)(b * N_NODES + n)) * 4) = ev;
}

extern "C" void kernel_launch(void* const* d_in, const int* in_sizes, int n_in,
                              void* d_out, int out_size, void* d_ws, size_t ws_size,
                              hipStream_t stream) {
    const float* query = (const float*)d_in[0];
    const float* key   = (const float*)d_in[1];
    const float* value = (const float*)d_in[2];
    const float* Wq    = (const float*)d_in[3];
    const float* bq    = (const float*)d_in[4];
    const float* Wv    = (const float*)d_in[5];
    const float* bv    = (const float*)d_in[6];
    const float* avec  = (const float*)d_in[7];
    float* out = (float*)d_out;
    float* e_out = out + B_SZ * HD;

    char* ws = (char*)d_ws;
    unsigned short* WqP = (unsigned short*)ws;               // 128 KB
    float* hqb    = (float*)(ws + 131072);                   // 32 KB
    float* s      = (float*)(ws + 163840);                   // 4 MB
    float* pml    = (float*)(ws + 163840 + 4194304);         // 256 KB
    float* sc     = (float*)(ws + 163840 + 4194304 + 262144);// 1 KB
    float* p_part = (float*)(ws + 163840 + 4194304 + 262144 + 4096); // 32 MB

    prep_kernel<<<64, 256, 0, stream>>>(query, Wq, bq, WqP, hqb);
    fused_kernel<<<B_SZ * 256, 256, 0, stream>>>(key, value, WqP, hqb, avec, s, p_part, pml);
    final_kernel<<<B_SZ * NUM_HEADS, 256, 0, stream>>>(p_part, pml, Wv, bv, out, sc);
    epass_kernel<<<B_SZ * 32, 256, 0, stream>>>(s, sc, out + B_SZ * HD);
}

// Round 7
// 188.787 us; speedup vs baseline: 1.0013x; 1.0013x over previous
//
#include <hip/hip_runtime.h>
#include <hip/hip_bf16.h>

#define NUM_HEADS 4
#define HD 256
#define QD 256
#define VD 256
#define B_SZ 32
#define N_NODES 8192
#define NEG_SLOPE 0.2f

typedef short bf16x8 __attribute__((ext_vector_type(8)));
typedef float f32x4 __attribute__((ext_vector_type(4)));

static __device__ __forceinline__ unsigned short f2bf(float f) {
    __hip_bfloat16 h = __float2bfloat16(f);
    return *reinterpret_cast<unsigned short*>(&h);
}

// async global->LDS, 16B per lane; LDS dest = uniform base + lane*16 (m104)
static __device__ __forceinline__ void gload_lds16(const float* g, float* l) {
    __builtin_amdgcn_global_load_lds(
        (const __attribute__((address_space(1))) void*)g,
        (__attribute__((address_space(3))) void*)l, 16, 0, 0);
}

// ---------------------------------------------------------------------------
// Kernel 1: prep
// ---------------------------------------------------------------------------
__global__ __launch_bounds__(256)
void prep_kernel(const float* __restrict__ query,
                 const float* __restrict__ Wq,
                 const float* __restrict__ bq,
                 unsigned short* __restrict__ WqP,
                 float* __restrict__ hqb) {
    int blk = blockIdx.x;
    int tid = threadIdx.x;
    if (blk < 32) {
        int b = blk, col = tid;
        float acc = 2.0f * bq[col];
#pragma unroll 16
        for (int k = 0; k < QD; ++k)
            acc += query[b * QD + k] * Wq[k * HD + col];
        hqb[b * HD + col] = acc;
    } else {
        int idx = blk - 32;
        int kstep = idx >> 2, g = idx & 3;
        int col = tid;
        unsigned short v[8];
#pragma unroll
        for (int j = 0; j < 8; ++j)
            v[j] = f2bf(Wq[(kstep * 32 + g * 8 + j) * HD + col]);
        *reinterpret_cast<uint4*>(WqP + kstep * 8192 + col * 32 + g * 8) =
            *reinterpret_cast<uint4*>(v);
    }
}

// ---------------------------------------------------------------------------
// Kernel 2 (FUSED flash, async): block = (b, 32-row chunk), grid 8192.
//  A) issue 8 async global_load_lds for this wave's value rows (fire&forget)
//  B) stage key tile bf16 (reg path)  C) lgkmcnt(0)+raw barrier (NO vmcnt
//  drain -> value stays in flight)  D) MFMA with reg-double-buffered WqP
//  E) epilogue -> esr  F) chunk softmax -> ese,pml  G) vmcnt(0)+lgkmcnt(0)
//  +raw barrier  H) coalesced s store  I) PV from LDS value  J) reduce.
// ---------------------------------------------------------------------------
__global__ __launch_bounds__(256)
void fused_kernel(const float* __restrict__ key,
                  const float* __restrict__ value,
                  const unsigned short* __restrict__ WqP,
                  const float* __restrict__ hqb,
                  const float* __restrict__ avec,
                  float* __restrict__ s,
                  float* __restrict__ p_part,
                  float* __restrict__ pml) {
    __shared__ __align__(16) char smemA[17920];
    __shared__ __align__(16) float vtf[32][256];                                  // 32 KB, separate object
    unsigned short (*kt)[264] = reinterpret_cast<unsigned short(*)[264]>(smemA);  // 16896 B
    float (*esr)[4] = reinterpret_cast<float(*)[4]>(smemA + 16896);               // raw scores
    float (*ese)[4] = reinterpret_cast<float(*)[4]>(smemA + 17408);               // exp scores
    float (*red)[4][260] = reinterpret_cast<float(*)[4][260]>(smemA);             // alias kt (post-barrier)

    int bid = blockIdx.x;
    int b = bid >> 8;
    int n0 = (bid & 255) * 32;
    int tid = threadIdx.x;
    int w = tid >> 6, lane = tid & 63;
    int col16 = lane & 15, g = lane >> 4;

    // ---- A) async value: wave w owns rows [w*8, w*8+8)
    {
        const float* vb = value + ((size_t)(b * N_NODES + n0 + w * 8)) * VD + lane * 4;
#pragma unroll
        for (int r = 0; r < 8; ++r)
            gload_lds16(vb + (size_t)r * VD, &vtf[w * 8 + r][0]);
    }

    // ---- B) stage 32x256 key tile (reg path, two halves)
    {
        int row = tid >> 3, c0 = (tid & 7) * 32;
        const float* kb = key + ((size_t)(b * N_NODES + n0 + row)) * QD + c0;
#pragma unroll
        for (int half = 0; half < 2; ++half) {
            float4 f[4];
#pragma unroll
            for (int i = 0; i < 4; ++i)
                f[i] = *reinterpret_cast<const float4*>(kb + half * 16 + i * 4);
            unsigned int u[8];
#pragma unroll
            for (int j = 0; j < 8; ++j) {
                float lo = (&f[j >> 1].x)[(j & 1) * 2];
                float hi = (&f[j >> 1].x)[(j & 1) * 2 + 1];
                asm("v_cvt_pk_bf16_f32 %0, %1, %2" : "=v"(u[j]) : "v"(lo), "v"(hi));
            }
#pragma unroll
            for (int i = 0; i < 2; ++i) {
                uint4 st = {u[i * 4], u[i * 4 + 1], u[i * 4 + 2], u[i * 4 + 3]};
                *reinterpret_cast<uint4*>(&kt[row][c0 + half * 16 + i * 8]) = st;
            }
        }
    }

    // ---- preload ks=0 B-fragments (in flight across the barrier)
    bf16x8 bcur[4];
    {
        const unsigned short* wp = WqP + w * 2048 + g * 8;
#pragma unroll
        for (int ct = 0; ct < 4; ++ct)
            bcur[ct] = *reinterpret_cast<const bf16x8*>(wp + (ct * 16 + col16) * 32);
    }

    // ---- C) staging barrier WITHOUT vmcnt drain (value stays in flight)
    __builtin_amdgcn_sched_barrier(0);
    asm volatile("s_waitcnt lgkmcnt(0)" ::: "memory");
    __builtin_amdgcn_s_barrier();
    __builtin_amdgcn_sched_barrier(0);

    // ---- D) MFMA: 32x64 C-tile per wave (head w), WqP double-buffered in regs
    f32x4 acc[2][4];
#pragma unroll
    for (int i = 0; i < 2; ++i)
#pragma unroll
        for (int j = 0; j < 4; ++j)
            acc[i][j] = (f32x4){0.f, 0.f, 0.f, 0.f};

#pragma unroll
    for (int ks = 0; ks < 8; ++ks) {
        bf16x8 bnext[4];
        if (ks < 7) {
            const unsigned short* wp = WqP + (ks + 1) * 8192 + w * 2048 + g * 8;
#pragma unroll
            for (int ct = 0; ct < 4; ++ct)
                bnext[ct] = *reinterpret_cast<const bf16x8*>(wp + (ct * 16 + col16) * 32);
        }
        bf16x8 afr0 = *reinterpret_cast<const bf16x8*>(&kt[col16][ks * 32 + g * 8]);
        bf16x8 afr1 = *reinterpret_cast<const bf16x8*>(&kt[16 + col16][ks * 32 + g * 8]);
#pragma unroll
        for (int ct = 0; ct < 4; ++ct) {
            acc[0][ct] = __builtin_amdgcn_mfma_f32_16x16x32_bf16(afr0, bcur[ct], acc[0][ct], 0, 0, 0);
            acc[1][ct] = __builtin_amdgcn_mfma_f32_16x16x32_bf16(afr1, bcur[ct], acc[1][ct], 0, 0, 0);
        }
#pragma unroll
        for (int ct = 0; ct < 4; ++ct) bcur[ct] = bnext[ct];
    }

    // ---- E) epilogue: leaky_relu + dot(a) + 16-lane reduce -> esr
    {
        float hq_[4], av[4];
#pragma unroll
        for (int ct = 0; ct < 4; ++ct) {
            hq_[ct] = hqb[b * HD + w * 64 + ct * 16 + col16];
            av[ct] = avec[ct * 16 + col16];
        }
#pragma unroll
        for (int rt = 0; rt < 2; ++rt) {
            float part[4] = {0.f, 0.f, 0.f, 0.f};
#pragma unroll
            for (int ct = 0; ct < 4; ++ct) {
#pragma unroll
                for (int r = 0; r < 4; ++r) {
                    float pre = acc[rt][ct][r] + hq_[ct];
                    float t = fmaxf(pre, NEG_SLOPE * pre);
                    part[r] += av[ct] * t;
                }
            }
#pragma unroll
            for (int off = 1; off < 16; off <<= 1)
#pragma unroll
                for (int r = 0; r < 4; ++r)
                    part[r] += __shfl_xor(part[r], off, 64);
            if (col16 == 0) {
                int rloc = rt * 16 + g * 4;
#pragma unroll
                for (int r = 0; r < 4; ++r) esr[rloc + r][w] = part[r];
            }
        }
    }

    // ---- F) chunk-local softmax for head w (own column; within-wave only)
    {
        float sv = esr[lane & 31][w];
        float m = sv;
#pragma unroll
        for (int off = 1; off < 32; off <<= 1) m = fmaxf(m, __shfl_xor(m, off, 64));
        float ep = __expf(sv - m);
        float ls = ep;
#pragma unroll
        for (int off = 1; off < 32; off <<= 1) ls += __shfl_xor(ls, off, 64);
        if (lane < 32) ese[lane][w] = ep;
        if (lane == 0) {
            pml[(size_t)bid * 8 + w] = m;
            pml[(size_t)bid * 8 + 4 + w] = ls;
        }
    }

    // ---- G) full drain + barrier: value in LDS, esr/ese visible to all
    __builtin_amdgcn_sched_barrier(0);
    asm volatile("s_waitcnt vmcnt(0) lgkmcnt(0)" ::: "memory");
    __builtin_amdgcn_s_barrier();
    __builtin_amdgcn_sched_barrier(0);

    // ---- H) coalesced raw-score store (reads other waves' esr: after barrier)
    if (tid < 128) {
        int h = tid >> 5, n = tid & 31;
        s[((size_t)(b * NUM_HEADS + h)) * N_NODES + n0 + n] = esr[n][h];
    }

    // ---- I) PV: wave w streams its 8 value rows from LDS (conflict-free)
    f32x4 a0 = {0.f, 0.f, 0.f, 0.f}, a1 = a0, a2 = a0, a3 = a0;
#pragma unroll
    for (int r = 0; r < 8; ++r) {
        int n = w * 8 + r;
        f32x4 v = *reinterpret_cast<const f32x4*>(&vtf[n][lane * 4]);
        f32x4 ev = *reinterpret_cast<const f32x4*>(&ese[n][0]);
        a0 += ev[0] * v;
        a1 += ev[1] * v;
        a2 += ev[2] * v;
        a3 += ev[3] * v;
    }
    *reinterpret_cast<f32x4*>(&red[w][0][lane * 4]) = a0;
    *reinterpret_cast<f32x4*>(&red[w][1][lane * 4]) = a1;
    *reinterpret_cast<f32x4*>(&red[w][2][lane * 4]) = a2;
    *reinterpret_cast<f32x4*>(&red[w][3][lane * 4]) = a3;
    __syncthreads();

    // ---- J) cross-wave reduce -> p_part
    float* pp = p_part + (size_t)bid * 1024;
#pragma unroll
    for (int h = 0; h < 4; ++h)
        pp[h * 256 + tid] = red[0][h][tid] + red[1][h][tid] + red[2][h][tid] + red[3][h][tid];
}

// ---------------------------------------------------------------------------
// Kernel 3: final. Per (b,h): global M, L; rescale-reduce p_part; @Wv+bias+relu.
// ---------------------------------------------------------------------------
__global__ __launch_bounds__(256)
void final_kernel(const float* __restrict__ p_part,
                  const float* __restrict__ pml,
                  const float* __restrict__ Wv,
                  const float* __restrict__ bv,
                  float* __restrict__ hout,
                  float* __restrict__ sc) {
    int bh = blockIdx.x;
    int b = bh >> 2, h = bh & 3;
    int tid = threadIdx.x;
    int wv = tid >> 6, lane = tid & 63;

    float mc = pml[((size_t)(b * 256 + tid)) * 8 + h];
    float lc = pml[((size_t)(b * 256 + tid)) * 8 + 4 + h];

    __shared__ float r4a[4], r4b[4];
    float M = mc;
#pragma unroll
    for (int off = 1; off < 64; off <<= 1) M = fmaxf(M, __shfl_xor(M, off, 64));
    if (lane == 0) r4a[wv] = M;
    __syncthreads();
    M = fmaxf(fmaxf(r4a[0], r4a[1]), fmaxf(r4a[2], r4a[3]));

    __shared__ float wfs[256];
    float wf = __expf(mc - M);
    wfs[tid] = wf;
    float Lp = wf * lc;
#pragma unroll
    for (int off = 1; off < 64; off <<= 1) Lp += __shfl_xor(Lp, off, 64);
    if (lane == 0) r4b[wv] = Lp;
    __syncthreads();
    float L = r4b[0] + r4b[1] + r4b[2] + r4b[3];
    float invL = 1.0f / L;
    if (tid == 0) {
        sc[bh * 2] = M;
        sc[bh * 2 + 1] = invL;
    }

    float acc = 0.f;
    const float* pp = p_part + ((size_t)(b * 256)) * 1024 + h * 256 + tid;
#pragma unroll 8
    for (int c = 0; c < 256; ++c)
        acc += wfs[c] * pp[(size_t)c * 1024];
    __shared__ float ps[256];
    ps[tid] = acc * invL;
    __syncthreads();

    int d = tid & 63, kr = tid >> 6;
    float a2 = 0.f;
#pragma unroll 8
    for (int k = kr * 64; k < kr * 64 + 64; ++k)
        a2 += ps[k] * Wv[k * HD + h * 64 + d];
    __shared__ float rs[4][64];
    rs[kr][d] = a2;
    __syncthreads();
    if (tid < 64) {
        float o = bv[h * 64 + tid] + rs[0][tid] + rs[1][tid] + rs[2][tid] + rs[3][tid];
        hout[b * HD + h * 64 + tid] = fmaxf(o, 0.f);
    }
}

// ---------------------------------------------------------------------------
// Kernel 4: e-pass. e_out[b,n,h] = exp(s[b,h,n]-M)*invL.
// ---------------------------------------------------------------------------
__global__ __launch_bounds__(256)
void epass_kernel(const float* __restrict__ s,
                  const float* __restrict__ sc,
                  float* __restrict__ e_out) {
    int bid = blockIdx.x;
    int b = bid >> 5, t = bid & 31;
    int n = t * 256 + threadIdx.x;
    float4 ev;
#pragma unroll
    for (int h = 0; h < 4; ++h) {
        float M = sc[(b * 4 + h) * 2];
        float invL = sc[(b * 4 + h) * 2 + 1];
        float sv = s[((size_t)(b * 4 + h)) * N_NODES + n];
        (&ev.x)[h] = __expf(sv - M) * invL;
    }
    *reinterpret_cast<float4*>(e_out + ((size_t)(b * N_NODES + n)) * 4) = ev;
}

extern "C" void kernel_launch(void* const* d_in, const int* in_sizes, int n_in,
                              void* d_out, int out_size, void* d_ws, size_t ws_size,
                              hipStream_t stream) {
    const float* query = (const float*)d_in[0];
    const float* key   = (const float*)d_in[1];
    const float* value = (const float*)d_in[2];
    const float* Wq    = (const float*)d_in[3];
    const float* bq    = (const float*)d_in[4];
    const float* Wv    = (const float*)d_in[5];
    const float* bv    = (const float*)d_in[6];
    const float* avec  = (const float*)d_in[7];
    float* out = (float*)d_out;

    char* ws = (char*)d_ws;
    unsigned short* WqP = (unsigned short*)ws;               // 128 KB
    float* hqb    = (float*)(ws + 131072);                   // 32 KB
    float* s      = (float*)(ws + 163840);                   // 4 MB
    float* pml    = (float*)(ws + 163840 + 4194304);         // 256 KB
    float* sc     = (float*)(ws + 163840 + 4194304 + 262144);// 1 KB
    float* p_part = (float*)(ws + 163840 + 4194304 + 262144 + 4096); // 32 MB

    prep_kernel<<<64, 256, 0, stream>>>(query, Wq, bq, WqP, hqb);
    fused_kernel<<<B_SZ * 256, 256, 0, stream>>>(key, value, WqP, hqb, avec, s, p_part, pml);
    final_kernel<<<B_SZ * NUM_HEADS, 256, 0, stream>>>(p_part, pml, Wv, bv, out, sc);
    epass_kernel<<<B_SZ * 32, 256, 0, stream>>>(s, sc, out + B_SZ * HD);
}